// Round 1
// baseline (603.708 us; speedup 1.0000x reference)
//
#include <hip/hip_runtime.h>
#include <cstddef>

#define N_NODES 50000
#define E_EDGES 1600000
#define HEADS 4
#define CPH 32
#define DIM 128
#define NEG_SLOPE 0.2f
#define LN_EPS 1e-5f

// ---------------- workspace layout (bytes) ----------------
// scal[0] = ew_sum (atomic), scal[4..7] = K[h]  (16B aligned for float4)
#define OFF_SCAL    0u
#define OFF_COUNTS  256u                       // N ints
#define OFF_OFFSETS 200448u                    // N+1 ints
#define OFF_CURSOR  400640u                    // N ints
#define OFF_BLKSUM  600832u                    // 256 ints
#define OFF_ASRC    602112u                    // N*4 floats
#define OFF_ADST    1402368u                   // N*4 floats
#define OFF_XP      2202624u                   // N*128 floats
#define OFF_SRCS    27802624u                  // E ints
#define OFF_LOGS    34202624u                  // E*4 floats  (end 59,802,624)

__device__ __forceinline__ float lrelu(float x) { return x > 0.f ? x : NEG_SLOPE * x; }

// K[h] = sum_c W_edge[h*32+c] * att_edge[h*32+c]
__global__ __launch_bounds__(128) void k_prep(const float* __restrict__ W_edge,
                                              const float* __restrict__ att_edge,
                                              float* __restrict__ scal) {
    int t = threadIdx.x;
    float p = W_edge[t] * att_edge[t];
    #pragma unroll
    for (int off = 16; off; off >>= 1) p += __shfl_down(p, off, 32);
    if ((t & 31) == 0) scal[4 + (t >> 5)] = p;
}

// sum(edge_weight) -> scal[0]
__global__ __launch_bounds__(256) void k_mean(const float* __restrict__ ew, float* __restrict__ scal) {
    size_t i = (size_t)blockIdx.x * blockDim.x + threadIdx.x;
    size_t stride = (size_t)gridDim.x * blockDim.x;
    float v = 0.f;
    for (size_t j = i; j < E_EDGES; j += stride) v += ew[j];
    #pragma unroll
    for (int off = 32; off; off >>= 1) v += __shfl_down(v, off, 64);
    if ((threadIdx.x & 63) == 0) atomicAdd(&scal[0], v);
}

// xp = x @ W ; a_src[n,h] = sum_c xp[n,h,c]*att_src[h,c] ; same a_dst
__global__ __launch_bounds__(128) void k_gemm(const float* __restrict__ x, const float* __restrict__ W,
                                              const float* __restrict__ att_src, const float* __restrict__ att_dst,
                                              float* __restrict__ xp, float* __restrict__ a_src,
                                              float* __restrict__ a_dst) {
    __shared__ float sW[64 * 128];  // 32 KB (half of K at a time)
    __shared__ float sx[16 * 128];  // 8 KB
    int t = threadIdx.x;
    int r0 = blockIdx.x * 16;
    int nr = min(16, N_NODES - r0);
    for (int i = t; i < nr * 128; i += 128) sx[i] = x[(size_t)r0 * 128 + i];
    float acc[16];
    #pragma unroll
    for (int r = 0; r < 16; r++) acc[r] = 0.f;
    for (int kc = 0; kc < 128; kc += 64) {
        __syncthreads();
        for (int i = t; i < 64 * 128; i += 128) sW[i] = W[(size_t)kc * 128 + i];
        __syncthreads();
        #pragma unroll 8
        for (int k = 0; k < 64; k++) {
            float w = sW[k * 128 + t];
            #pragma unroll
            for (int r = 0; r < 16; r++) acc[r] = fmaf(sx[r * 128 + kc + k], w, acc[r]);
        }
    }
    float as = att_src[t], ad = att_dst[t];
    for (int r = 0; r < nr; r++) {
        float v = acc[r];
        xp[(size_t)(r0 + r) * 128 + t] = v;
        float ps = v * as, pd = v * ad;
        #pragma unroll
        for (int off = 16; off; off >>= 1) {
            ps += __shfl_down(ps, off, 32);
            pd += __shfl_down(pd, off, 32);
        }
        if ((t & 31) == 0) {
            a_src[(size_t)(r0 + r) * 4 + (t >> 5)] = ps;
            a_dst[(size_t)(r0 + r) * 4 + (t >> 5)] = pd;
        }
    }
}

__global__ __launch_bounds__(256) void k_count(const int* __restrict__ ei, int* __restrict__ counts) {
    int e = blockIdx.x * 256 + threadIdx.x;
    if (e < E_EDGES) atomicAdd(&counts[ei[E_EDGES + e]], 1);
}

__device__ __forceinline__ int block_incl_scan256(int v, int t) {
    int lane = t & 63, wid = t >> 6;
    #pragma unroll
    for (int d = 1; d < 64; d <<= 1) {
        int u = __shfl_up(v, d, 64);
        if (lane >= d) v += u;
    }
    __shared__ int wsum[4];
    if (lane == 63) wsum[wid] = v;
    __syncthreads();
    int add = 0;
    #pragma unroll
    for (int w = 0; w < 4; w++)
        if (w < wid) add += wsum[w];
    return v + add;
}

__global__ __launch_bounds__(256) void k_scan1(const int* __restrict__ counts, int* __restrict__ offsets,
                                               int* __restrict__ blkSums) {
    int t = threadIdx.x;
    int idx = blockIdx.x * 256 + t;
    int v = (idx < N_NODES) ? counts[idx] : 0;
    int incl = block_incl_scan256(v, t);
    if (idx < N_NODES) offsets[idx] = incl - v;
    if (t == 255) blkSums[blockIdx.x] = incl;
}

__global__ __launch_bounds__(256) void k_scan2(int* __restrict__ blkSums, int* __restrict__ offsets, int nblk) {
    int t = threadIdx.x;
    int v = (t < nblk) ? blkSums[t] : 0;
    int incl = block_incl_scan256(v, t);
    if (t < nblk) blkSums[t] = incl - v;
    if (t == 255) offsets[N_NODES] = incl;
}

__global__ __launch_bounds__(256) void k_scan3(int* __restrict__ offsets, int* __restrict__ cursor,
                                               const int* __restrict__ blkSums) {
    int idx = blockIdx.x * 256 + threadIdx.x;
    if (idx < N_NODES) {
        int o = offsets[idx] + blkSums[blockIdx.x];
        offsets[idx] = o;
        cursor[idx] = o;
    }
}

// place each edge in its dst bucket; precompute leaky-relu logits for 4 heads
__global__ __launch_bounds__(256) void k_scatter(const int* __restrict__ ei, const float* __restrict__ ew,
                                                 const float* __restrict__ a_src, const float* __restrict__ a_dst,
                                                 const float* __restrict__ scal, int* __restrict__ cursor,
                                                 int* __restrict__ src_sorted, float* __restrict__ logits_s) {
    int e = blockIdx.x * 256 + threadIdx.x;
    if (e >= E_EDGES) return;
    int s = ei[e];
    int d = ei[E_EDGES + e];
    float w = ew[e];
    int pos = atomicAdd(&cursor[d], 1);
    src_sorted[pos] = s;
    float4 as = *(const float4*)(a_src + (size_t)4 * s);
    float4 ad = *(const float4*)(a_dst + (size_t)4 * d);
    float4 K = *(const float4*)(scal + 4);
    float4 lg;
    lg.x = lrelu(as.x + ad.x + K.x * w);
    lg.y = lrelu(as.y + ad.y + K.y * w);
    lg.z = lrelu(as.z + ad.z + K.z * w);
    lg.w = lrelu(as.w + ad.w + K.w * w);
    *(float4*)(logits_s + (size_t)4 * pos) = lg;
}

// one block (128 thr) per node: softmax over in-edges (+self loop), weighted
// gather of xp[src], bias + LayerNorm + ELU epilogue.
__global__ __launch_bounds__(128) void k_agg(const float* __restrict__ xp, const float* __restrict__ a_src,
                                             const float* __restrict__ a_dst, const int* __restrict__ offsets,
                                             const int* __restrict__ src_sorted, const float* __restrict__ logits_s,
                                             const float* __restrict__ scal, const float* __restrict__ bias,
                                             const float* __restrict__ gamma, const float* __restrict__ beta,
                                             float* __restrict__ out) {
    int n = blockIdx.x;
    int t = threadIdx.x;
    int h = t >> 5;
    __shared__ float red[128];
    __shared__ float lslS[4], mS[4], lS[4];

    int off = offsets[n];
    int cnt = offsets[n + 1] - off;

    float mean_ew = scal[0] * (1.0f / E_EDGES);
    float Kh = scal[4 + h];
    float lsl = lrelu(a_src[(size_t)n * 4 + h] + a_dst[(size_t)n * 4 + h] + Kh * mean_ew);
    if ((t & 31) == 0) lslS[h] = lsl;

    // pass 1: per-head max over edges.  thread layout: head hh=t&3, idx li=t>>2
    int hh = t & 3;
    int li = t >> 2;
    float mx = -3.4e38f;
    for (int i = li; i < cnt; i += 32) mx = fmaxf(mx, logits_s[(size_t)(off + i) * 4 + hh]);
    red[t] = mx;
    __syncthreads();
    #pragma unroll
    for (int s = 64; s >= 4; s >>= 1) {
        if (t < s) red[t] = fmaxf(red[t], red[t + s]);
        __syncthreads();
    }
    if (t < 4) mS[t] = fmaxf(red[t], lslS[t]);
    __syncthreads();

    // pass 1b: denom
    float mh1 = mS[hh];
    float sm = 0.f;
    for (int i = li; i < cnt; i += 32) sm += expf(logits_s[(size_t)(off + i) * 4 + hh] - mh1);
    red[t] = sm;
    __syncthreads();
    #pragma unroll
    for (int s = 64; s >= 4; s >>= 1) {
        if (t < s) red[t] += red[t + s];
        __syncthreads();
    }
    if (t < 4) lS[t] = red[t] + expf(lslS[t] - mS[t]);
    __syncthreads();

    // pass 2: weighted gather-accumulate (channel t = h*32+c)
    float mh = mS[h];
    float inv = 1.0f / (lS[h] + 1e-16f);
    float acc = expf(lsl - mh) * xp[(size_t)n * 128 + t];
    for (int i = 0; i < cnt; i++) {
        int s = src_sorted[off + i];
        float lg = logits_s[(size_t)(off + i) * 4 + h];
        acc = fmaf(expf(lg - mh), xp[(size_t)s * 128 + t], acc);
    }
    float y = acc * inv + bias[t];

    // LayerNorm over 128 channels
    red[t] = y;
    __syncthreads();
    #pragma unroll
    for (int s = 64; s >= 1; s >>= 1) {
        if (t < s) red[t] += red[t + s];
        __syncthreads();
    }
    float mu = red[0] * (1.f / 128.f);
    __syncthreads();
    float dv = y - mu;
    red[t] = dv * dv;
    __syncthreads();
    #pragma unroll
    for (int s = 64; s >= 1; s >>= 1) {
        if (t < s) red[t] += red[t + s];
        __syncthreads();
    }
    float var = red[0] * (1.f / 128.f);
    float o = dv * rsqrtf(var + LN_EPS) * gamma[t] + beta[t];
    out[(size_t)n * 128 + t] = o > 0.f ? o : expm1f(o);
}

extern "C" void kernel_launch(void* const* d_in, const int* in_sizes, int n_in,
                              void* d_out, int out_size, void* d_ws, size_t ws_size,
                              hipStream_t stream) {
    const float* x        = (const float*)d_in[0];
    const int*   ei       = (const int*)d_in[1];
    const float* ew       = (const float*)d_in[2];
    const float* W        = (const float*)d_in[3];
    const float* att_src  = (const float*)d_in[4];
    const float* att_dst  = (const float*)d_in[5];
    const float* W_edge   = (const float*)d_in[6];
    const float* att_edge = (const float*)d_in[7];
    const float* bias     = (const float*)d_in[8];
    const float* gamma    = (const float*)d_in[9];
    const float* beta     = (const float*)d_in[10];
    float* out = (float*)d_out;

    char* ws = (char*)d_ws;
    float* scal      = (float*)(ws + OFF_SCAL);
    int*   counts    = (int*)(ws + OFF_COUNTS);
    int*   offsets   = (int*)(ws + OFF_OFFSETS);
    int*   cursor    = (int*)(ws + OFF_CURSOR);
    int*   blkSums   = (int*)(ws + OFF_BLKSUM);
    float* a_src     = (float*)(ws + OFF_ASRC);
    float* a_dst     = (float*)(ws + OFF_ADST);
    float* xp        = (float*)(ws + OFF_XP);
    int*   src_sorted= (int*)(ws + OFF_SRCS);
    float* logits_s  = (float*)(ws + OFF_LOGS);

    // zero ew_sum accumulator + counts
    hipMemsetAsync(ws, 0, OFF_COUNTS + (size_t)N_NODES * 4, stream);

    k_prep<<<1, 128, 0, stream>>>(W_edge, att_edge, scal);
    k_mean<<<1024, 256, 0, stream>>>(ew, scal);
    k_gemm<<<(N_NODES + 15) / 16, 128, 0, stream>>>(x, W, att_src, att_dst, xp, a_src, a_dst);
    k_count<<<(E_EDGES + 255) / 256, 256, 0, stream>>>(ei, counts);
    const int NB1 = (N_NODES + 255) / 256;  // 196
    k_scan1<<<NB1, 256, 0, stream>>>(counts, offsets, blkSums);
    k_scan2<<<1, 256, 0, stream>>>(blkSums, offsets, NB1);
    k_scan3<<<NB1, 256, 0, stream>>>(offsets, cursor, blkSums);
    k_scatter<<<(E_EDGES + 255) / 256, 256, 0, stream>>>(ei, ew, a_src, a_dst, scal, cursor,
                                                         src_sorted, logits_s);
    k_agg<<<N_NODES, 128, 0, stream>>>(xp, a_src, a_dst, offsets, src_sorted, logits_s, scal,
                                       bias, gamma, beta, out);
}